// Round 5
// baseline (715.601 us; speedup 1.0000x reference)
//
#include <hip/hip_runtime.h>
#include <math.h>

// B=32, OBS=768, D=512, V=64
// Outputs (f32): h[32*512] | pred[32*768] | graph[64*64] | reasoning[32*512]
// Single persistent kernel, 1024 blocks x 256 thr (4096 waves), software grid
// barriers between the 5 dependency phases.

#define NBLK 1024

#if __has_builtin(__builtin_amdgcn_exp2f)
#define EXP2F __builtin_amdgcn_exp2f
#else
#define EXP2F exp2f
#endif

__device__ __forceinline__ float gelu_exact(float x) {
    return 0.5f * x * (1.f + erff(x * 0.70710678118654752f));
}
__device__ __forceinline__ float sigmoid_fast(float v) {
    return __builtin_amdgcn_rcpf(1.f + EXP2F(-1.442695041f * v));
}
__device__ __forceinline__ float tanh_fast(float v) {
    return fmaf(-2.f, __builtin_amdgcn_rcpf(1.f + EXP2F(2.885390082f * v)), 1.f);
}

// Grid barrier: one counter per phase boundary (single-use per launch; ws is
// re-zeroed every call). launch_bounds(256,4) guarantees 4 blocks/CU => all
// 1024 blocks co-resident. __threadfence = agent-scope fence (cross-XCD).
__device__ __forceinline__ void gbar(unsigned* cnt) {
    __syncthreads();
    if (threadIdx.x == 0) {
        __threadfence();
        __hip_atomic_fetch_add(cnt, 1u, __ATOMIC_RELEASE, __HIP_MEMORY_SCOPE_AGENT);
        while (__hip_atomic_load(cnt, __ATOMIC_RELAXED, __HIP_MEMORY_SCOPE_AGENT) < (unsigned)NBLK)
            __builtin_amdgcn_s_sleep(2);
        __threadfence();
    }
    __syncthreads();
}

// Wave-tile GEMM: one wave -> out[b0..b0+7][o0..o0+3]. K = NF4*256 floats.
// Lane owns float4 indices {c*64+lane}: all global loads coalesced (1KB/instr).
template<int NF4, int ACT>
__device__ __forceinline__ void wg4(int unit,
        const float* __restrict__ A, int lda,
        const float* __restrict__ W, int ldw,
        const float* __restrict__ bias,
        float* __restrict__ out, int ldo, int oblocks) {
    int lane = threadIdx.x & 63;
    int ob = unit % oblocks, bg = unit / oblocks;
    int o0 = ob * 4, b0 = bg * 8;

    float4 w[4][NF4];
#pragma unroll
    for (int r = 0; r < 4; ++r) {
        const float4* wr = reinterpret_cast<const float4*>(W + (o0 + r) * ldw);
#pragma unroll
        for (int c = 0; c < NF4; ++c) w[r][c] = wr[c * 64 + lane];
    }
#pragma unroll 2
    for (int bi = 0; bi < 8; ++bi) {
        const float4* ar = reinterpret_cast<const float4*>(A + (b0 + bi) * lda);
        float4 a[NF4];
#pragma unroll
        for (int c = 0; c < NF4; ++c) a[c] = ar[c * 64 + lane];
        float s[4];
#pragma unroll
        for (int r = 0; r < 4; ++r) {
            float acc = 0.f;
#pragma unroll
            for (int c = 0; c < NF4; ++c) {
                acc = fmaf(a[c].x, w[r][c].x, acc);
                acc = fmaf(a[c].y, w[r][c].y, acc);
                acc = fmaf(a[c].z, w[r][c].z, acc);
                acc = fmaf(a[c].w, w[r][c].w, acc);
            }
            s[r] = acc;
        }
#pragma unroll
        for (int m = 1; m < 64; m <<= 1) {
#pragma unroll
            for (int r = 0; r < 4; ++r) s[r] += __shfl_xor(s[r], m, 64);
        }
        if (lane == 0) {
#pragma unroll
            for (int r = 0; r < 4; ++r) {
                float v = s[r] + (bias ? bias[o0 + r] : 0.f);
                if (ACT) v = gelu_exact(v);
                out[(b0 + bi) * ldo + o0 + r] = v;
            }
        }
    }
}

// GRU unit: one wave -> one output column o, 8 b rows. gi = [z||action]@wih^T,
// h0 = 0 => gh = bhh. 2048 units (512 o x 4 bgroups).
__device__ __forceinline__ void gru_unit(int u,
        const float* __restrict__ z, const float* __restrict__ action,
        const float* __restrict__ wih, const float* __restrict__ bih,
        const float* __restrict__ bhh,
        float* __restrict__ h, float* __restrict__ ha) {
    int lane = threadIdx.x & 63;
    int o = u & 511, bg = u >> 9;
    int b0 = bg * 8;

    float4 wz[3][2], wa[3][2];
#pragma unroll
    for (int g = 0; g < 3; ++g) {
        const float* row = wih + (g * 512 + o) * 1024;
        const float4* rz = reinterpret_cast<const float4*>(row);
        const float4* ra = reinterpret_cast<const float4*>(row + 512);
#pragma unroll
        for (int c = 0; c < 2; ++c) { wz[g][c] = rz[c * 64 + lane]; wa[g][c] = ra[c * 64 + lane]; }
    }
    float bz0 = bih[o] + bhh[o];
    float bz1 = bih[512 + o] + bhh[512 + o];
    float bz2 = bih[1024 + o];
    float bhn = bhh[1024 + o];

#pragma unroll 2
    for (int bi = 0; bi < 8; ++bi) {
        int b = b0 + bi;
        const float4* az = reinterpret_cast<const float4*>(z + b * 512);
        const float4* aa = reinterpret_cast<const float4*>(action + b * 512);
        float4 vz[2] = {az[lane], az[64 + lane]};
        float4 va[2] = {aa[lane], aa[64 + lane]};
        float s[3];
#pragma unroll
        for (int g = 0; g < 3; ++g) {
            float acc = 0.f;
#pragma unroll
            for (int c = 0; c < 2; ++c) {
                acc = fmaf(vz[c].x, wz[g][c].x, acc);
                acc = fmaf(vz[c].y, wz[g][c].y, acc);
                acc = fmaf(vz[c].z, wz[g][c].z, acc);
                acc = fmaf(vz[c].w, wz[g][c].w, acc);
                acc = fmaf(va[c].x, wa[g][c].x, acc);
                acc = fmaf(va[c].y, wa[g][c].y, acc);
                acc = fmaf(va[c].z, wa[g][c].z, acc);
                acc = fmaf(va[c].w, wa[g][c].w, acc);
            }
            s[g] = acc;
        }
#pragma unroll
        for (int m = 1; m < 64; m <<= 1) {
#pragma unroll
            for (int g = 0; g < 3; ++g) s[g] += __shfl_xor(s[g], m, 64);
        }
        if (lane == 0) {
            float r  = sigmoid_fast(s[0] + bz0);
            float uu = sigmoid_fast(s[1] + bz1);
            float n  = tanh_fast(s[2] + bz2 + r * bhn);
            float hv = (1.f - uu) * n;
            h[b * 512 + o]  = hv;
            ha[b * 512 + o] = hv + action[b * 512 + o];
        }
    }
}

// Score unit: one wave -> one (i,j), all 32 b. lane owns d in [16*lane,16*lane+16).
// gelu(x) ~= x/(1+2^(NK*x)); one rcp per 2 elements via shared denominator.
__device__ __forceinline__ void score_unit(int su,
        const float* __restrict__ Ea, const float* __restrict__ Eb,
        const float* __restrict__ Cc, const float* __restrict__ w2,
        const float* __restrict__ b2, float* __restrict__ graph) {
    int i = su >> 6, j = su & 63;
    int lane = threadIdx.x & 63;
    int d0 = lane << 4;

    const float4* Ea4 = reinterpret_cast<const float4*>(Ea + i * 1024 + d0);
    const float4* Eb4 = reinterpret_cast<const float4*>(Eb + j * 1024 + d0);
    const float4* W4  = reinterpret_cast<const float4*>(w2 + d0);

    float base[16], wv[16];
#pragma unroll
    for (int c = 0; c < 4; ++c) {
        float4 e = Ea4[c], f = Eb4[c], w = W4[c];
        base[4 * c + 0] = e.x + f.x; base[4 * c + 1] = e.y + f.y;
        base[4 * c + 2] = e.z + f.z; base[4 * c + 3] = e.w + f.w;
        wv[4 * c + 0] = w.x; wv[4 * c + 1] = w.y;
        wv[4 * c + 2] = w.z; wv[4 * c + 3] = w.w;
    }

    const float NK = -2.4554274f;  // -1.702 * log2(e)
    float bsc = b2[0];
    float gsum = 0.f;
    const float4* p = reinterpret_cast<const float4*>(Cc + d0);
    float4 n0 = p[0], n1 = p[1], n2 = p[2], n3 = p[3];

    for (int b = 0; b < 32; ++b) {
        float cc[16];
        cc[0]  = n0.x; cc[1]  = n0.y; cc[2]  = n0.z; cc[3]  = n0.w;
        cc[4]  = n1.x; cc[5]  = n1.y; cc[6]  = n1.z; cc[7]  = n1.w;
        cc[8]  = n2.x; cc[9]  = n2.y; cc[10] = n2.z; cc[11] = n2.w;
        cc[12] = n3.x; cc[13] = n3.y; cc[14] = n3.z; cc[15] = n3.w;
        if (b < 31) {
            const float4* q = reinterpret_cast<const float4*>(Cc + (b + 1) * 1024 + d0);
            n0 = q[0]; n1 = q[1]; n2 = q[2]; n3 = q[3];
        }
        float s = 0.f;
#pragma unroll
        for (int e = 0; e < 16; e += 2) {
            float xa = cc[e]     + base[e];
            float xb = cc[e + 1] + base[e + 1];
            float ta = EXP2F(xa * NK);
            float tb = EXP2F(xb * NK);
            float da = 1.f + ta, db = 1.f + tb;
            float rr = __builtin_amdgcn_rcpf(da * db);
            float t1 = xa * wv[e];
            float t2 = xb * wv[e + 1];
            float num = fmaf(t1, db, t2 * da);
            s = fmaf(num, rr, s);
        }
#pragma unroll
        for (int m = 32; m >= 1; m >>= 1) s += __shfl_xor(s, m, 64);
        if (lane == 0) gsum += sigmoid_fast(s + bsc);
    }
    if (lane == 0) graph[i * 64 + j] = gsum * 0.03125f;
}

__global__ void __launch_bounds__(256, 4) fused_kernel(
    const float* __restrict__ obs, const float* __restrict__ action,
    const float* __restrict__ embed, const float* __restrict__ sc_w1,
    const float* __restrict__ sc_b1, const float* __restrict__ sc_w2,
    const float* __restrict__ sc_b2, const float* __restrict__ enc_w1,
    const float* __restrict__ enc_b1, const float* __restrict__ enc_w2,
    const float* __restrict__ enc_b2, const float* __restrict__ wih,
    const float* __restrict__ bih, const float* __restrict__ bhh,
    const float* __restrict__ dec_w, const float* __restrict__ dec_b,
    const float* __restrict__ rs_w1, const float* __restrict__ rs_b1,
    const float* __restrict__ rs_w2, const float* __restrict__ rs_b2,
    float* __restrict__ ws, float* __restrict__ out) {
    unsigned* cnt = reinterpret_cast<unsigned*>(ws);
    float* h1 = ws + 64;       // 32x1024
    float* z  = ws + 32832;    // 32x512
    float* ha = ws + 49216;    // 32x512
    float* r1 = ws + 65600;    // 32x512
    float* Cc = ws + 81984;    // 32x1024
    float* Ea = ws + 114752;   // 64x1024
    float* Eb = ws + 180288;   // 64x1024

    float* h_out     = out;            // 32x512
    float* pred      = out + 16384;    // 32x768
    float* graph     = out + 40960;    // 64x64
    float* reasoning = out + 45056;    // 32x512

    const int wid = blockIdx.x * 4 + (threadIdx.x >> 6);  // 0..4095

    // P1: enc1 (1024 units) + Ea (2048) + Eb (2048) = 5120 units
    for (int u = wid; u < 5120; u += 4096) {
        if (u < 1024)      wg4<3, 1>(u,        obs,   768, enc_w1,      768,  enc_b1, h1, 1024, 256);
        else if (u < 3072) wg4<2, 0>(u - 1024, embed, 512, sc_w1,       1536, sc_b1,  Ea, 1024, 256);
        else               wg4<2, 0>(u - 3072, embed, 512, sc_w1 + 512, 1536, nullptr, Eb, 1024, 256);
    }
    gbar(cnt + 0);

    // P2: z = h1 @ enc_w2^T + b (512 units)
    if (wid < 512) wg4<4, 0>(wid, h1, 1024, enc_w2, 1024, enc_b2, z, 512, 128);
    gbar(cnt + 1);

    // P3: gi + GRU (2048 units)
    if (wid < 2048) gru_unit(wid, z, action, wih, bih, bhh, h_out, ha);
    gbar(cnt + 2);

    // P4: dec (768) + rs1 (512) + Cc (1024) = 2304 units
    if (wid < 2304) {
        if (wid < 768)       wg4<2, 0>(wid,        h_out, 512, dec_w,        512,  dec_b,  pred, 768, 192);
        else if (wid < 1280) wg4<2, 1>(wid - 768,  h_out, 512, rs_w1,        512,  rs_b1,  r1,   512, 128);
        else                 wg4<2, 0>(wid - 1280, ha,    512, sc_w1 + 1024, 1536, nullptr, Cc,  1024, 256);
    }
    gbar(cnt + 3);

    // P5: rs2 (512 units) + score (4096 units) = 4608
    for (int u = wid; u < 4608; u += 4096) {
        if (u < 512) wg4<2, 0>(u, r1, 512, rs_w2, 512, rs_b2, reasoning, 512, 128);
        else         score_unit(u - 512, Ea, Eb, Cc, sc_w2, sc_b2, graph);
    }
}

extern "C" void kernel_launch(void* const* d_in, const int* in_sizes, int n_in,
                              void* d_out, int out_size, void* d_ws, size_t ws_size,
                              hipStream_t stream) {
    const float* obs     = (const float*)d_in[0];
    const float* action  = (const float*)d_in[1];
    const float* embed   = (const float*)d_in[2];
    const float* sc_w1   = (const float*)d_in[3];
    const float* sc_b1   = (const float*)d_in[4];
    const float* sc_w2   = (const float*)d_in[5];
    const float* sc_b2   = (const float*)d_in[6];
    const float* enc_w1  = (const float*)d_in[7];
    const float* enc_b1  = (const float*)d_in[8];
    const float* enc_w2  = (const float*)d_in[9];
    const float* enc_b2  = (const float*)d_in[10];
    const float* gru_wih = (const float*)d_in[11];
    const float* gru_bih = (const float*)d_in[13];
    const float* gru_bhh = (const float*)d_in[14];
    const float* dec_w   = (const float*)d_in[15];
    const float* dec_b   = (const float*)d_in[16];
    const float* rs_w1   = (const float*)d_in[17];
    const float* rs_b1   = (const float*)d_in[18];
    const float* rs_w2   = (const float*)d_in[19];
    const float* rs_b2   = (const float*)d_in[20];

    // zero the barrier counters (ws is poisoned 0xAA before every launch)
    hipMemsetAsync(d_ws, 0, 256, stream);

    fused_kernel<<<NBLK, 256, 0, stream>>>(
        obs, action, embed, sc_w1, sc_b1, sc_w2, sc_b2,
        enc_w1, enc_b1, enc_w2, enc_b2,
        gru_wih, gru_bih, gru_bhh, dec_w, dec_b,
        rs_w1, rs_b1, rs_w2, rs_b2,
        (float*)d_ws, (float*)d_out);
}

// Round 6
// 210.929 us; speedup vs baseline: 3.3926x; 3.3926x over previous
//
#include <hip/hip_runtime.h>
#include <math.h>

// B=32, OBS=768, D=512, V=64
// Outputs (f32): h[32*512] | pred[32*768] | graph[64*64] | reasoning[32*512]
// 5 kernels (chain depth is 5: enc1 -> enc2 -> gru -> mid -> score).
// NOTE (round 5): persistent kernel + agent-scope grid barriers = ~145us/barrier
// on gfx950 (L2 wb/inv per block + same-line spin contention). Do not retry.

#if __has_builtin(__builtin_amdgcn_exp2f)
#define EXP2F __builtin_amdgcn_exp2f
#else
#define EXP2F exp2f
#endif

typedef float f32x2 __attribute__((ext_vector_type(2)));

__device__ __forceinline__ float gelu_exact(float x) {
    return 0.5f * x * (1.f + erff(x * 0.70710678118654752f));
}
__device__ __forceinline__ float sigmoid_fast(float v) {
    return __builtin_amdgcn_rcpf(1.f + EXP2F(-1.442695041f * v));
}
__device__ __forceinline__ float tanh_fast(float v) {
    return fmaf(-2.f, __builtin_amdgcn_rcpf(1.f + EXP2F(2.885390082f * v)), 1.f);
}

// Wave-tile GEMM: one wave -> out[b0..b0+7][o0..o0+7] = act(A[b,:]·W[o,:]+bias[o]).
// K = NF4*256 floats. Lane owns float4 indices {c*64+lane}: all loads coalesced.
template<int NF4, int ACT>
__device__ __forceinline__ void wgemm(int wid,
        const float* __restrict__ A, int lda,
        const float* __restrict__ W, int ldw,
        const float* __restrict__ bias,
        float* __restrict__ out, int ldo,
        int oblocks) {
    int lane = threadIdx.x & 63;
    int oblock = wid % oblocks;
    int bgroup = wid / oblocks;
    int o0 = oblock * 8, b0 = bgroup * 8;

    float4 w[8][NF4];
#pragma unroll
    for (int r = 0; r < 8; ++r) {
        const float4* wr = reinterpret_cast<const float4*>(W + (o0 + r) * ldw);
#pragma unroll
        for (int c = 0; c < NF4; ++c) w[r][c] = wr[c * 64 + lane];
    }
#pragma unroll 2
    for (int bi = 0; bi < 8; ++bi) {
        const float4* ar = reinterpret_cast<const float4*>(A + (b0 + bi) * lda);
        float4 a[NF4];
#pragma unroll
        for (int c = 0; c < NF4; ++c) a[c] = ar[c * 64 + lane];
        float s[8];
#pragma unroll
        for (int r = 0; r < 8; ++r) {
            float acc = 0.f;
#pragma unroll
            for (int c = 0; c < NF4; ++c) {
                acc = fmaf(a[c].x, w[r][c].x, acc);
                acc = fmaf(a[c].y, w[r][c].y, acc);
                acc = fmaf(a[c].z, w[r][c].z, acc);
                acc = fmaf(a[c].w, w[r][c].w, acc);
            }
            s[r] = acc;
        }
#pragma unroll
        for (int m = 1; m < 64; m <<= 1) {
#pragma unroll
            for (int r = 0; r < 8; ++r) s[r] += __shfl_xor(s[r], m, 64);
        }
        if (lane == 0) {
#pragma unroll
            for (int r = 0; r < 8; ++r) {
                float v = s[r] + (bias ? bias[o0 + r] : 0.f);
                if (ACT) v = gelu_exact(v);
                out[(b0 + bi) * ldo + o0 + r] = v;
            }
        }
    }
}

// K1: enc1 (512 w) + Ea (1024) + Eb (1024) + gia = action@wih[:,512:]^T + bih (768)
// = 3328 waves = 832 blocks
__global__ void __launch_bounds__(256) front_kernel(
    const float* __restrict__ obs, const float* __restrict__ enc_w1,
    const float* __restrict__ enc_b1, float* __restrict__ h1,
    const float* __restrict__ embed, const float* __restrict__ sc_w1,
    const float* __restrict__ sc_b1, float* __restrict__ Ea, float* __restrict__ Eb,
    const float* __restrict__ action, const float* __restrict__ wih,
    const float* __restrict__ bih, float* __restrict__ gia) {
    int wid = blockIdx.x * 4 + (threadIdx.x >> 6);
    if (wid < 512) {
        wgemm<3, 1>(wid, obs, 768, enc_w1, 768, enc_b1, h1, 1024, 128);
    } else if (wid < 1536) {
        wgemm<2, 0>(wid - 512, embed, 512, sc_w1, 1536, sc_b1, Ea, 1024, 128);
    } else if (wid < 2560) {
        wgemm<2, 0>(wid - 1536, embed, 512, sc_w1 + 512, 1536, nullptr, Eb, 1024, 128);
    } else {
        wgemm<2, 0>(wid - 2560, action, 512, wih + 512, 1024, bih, gia, 1536, 192);
    }
}

// K2: z = h1 @ enc_w2^T + b2. 256 waves = 64 blocks
__global__ void __launch_bounds__(256) enc2_kernel(
    const float* __restrict__ h1, const float* __restrict__ enc_w2,
    const float* __restrict__ enc_b2, float* __restrict__ z) {
    int wid = blockIdx.x * 4 + (threadIdx.x >> 6);
    wgemm<4, 0>(wid, h1, 1024, enc_w2, 1024, enc_b2, z, 512, 64);
}

// K3: z-half of gi + GRU. Wave = opair (2 o x 3 gates = 6 rows, K=512) x 8 b.
// 256 opairs x 4 bgroups = 1024 waves = 256 blocks. h0=0 => gh = bhh.
__global__ void __launch_bounds__(256) gigru_kernel(
    const float* __restrict__ z, const float* __restrict__ wih,
    const float* __restrict__ gia, const float* __restrict__ bhh,
    const float* __restrict__ action, float* __restrict__ h, float* __restrict__ ha) {
    int wid = blockIdx.x * 4 + (threadIdx.x >> 6);
    int lane = threadIdx.x & 63;
    int opair = wid & 255;
    int bg = wid >> 8;
    int o0 = opair * 2, b0 = bg * 8;

    int rows[6] = {o0, o0 + 1, 512 + o0, 513 + o0, 1024 + o0, 1025 + o0};
    float4 w[6][2];
#pragma unroll
    for (int r = 0; r < 6; ++r) {
        const float4* wr = reinterpret_cast<const float4*>(wih + rows[r] * 1024);
#pragma unroll
        for (int c = 0; c < 2; ++c) w[r][c] = wr[c * 64 + lane];
    }
    float bhr0 = bhh[o0],        bhr1 = bhh[o0 + 1];
    float bhu0 = bhh[512 + o0],  bhu1 = bhh[513 + o0];
    float bhn0 = bhh[1024 + o0], bhn1 = bhh[1025 + o0];

#pragma unroll 2
    for (int bi = 0; bi < 8; ++bi) {
        int b = b0 + bi;
        const float4* ar = reinterpret_cast<const float4*>(z + b * 512);
        float4 a[2] = {ar[lane], ar[64 + lane]};
        float s[6];
#pragma unroll
        for (int r = 0; r < 6; ++r) {
            float acc = 0.f;
#pragma unroll
            for (int c = 0; c < 2; ++c) {
                acc = fmaf(a[c].x, w[r][c].x, acc);
                acc = fmaf(a[c].y, w[r][c].y, acc);
                acc = fmaf(a[c].z, w[r][c].z, acc);
                acc = fmaf(a[c].w, w[r][c].w, acc);
            }
            s[r] = acc;
        }
#pragma unroll
        for (int m = 1; m < 64; m <<= 1) {
#pragma unroll
            for (int r = 0; r < 6; ++r) s[r] += __shfl_xor(s[r], m, 64);
        }
        if (lane == 0) {
            const float* gb = gia + b * 1536;
            float r0 = sigmoid_fast(s[0] + gb[o0]        + bhr0);
            float r1 = sigmoid_fast(s[1] + gb[o0 + 1]    + bhr1);
            float u0 = sigmoid_fast(s[2] + gb[512 + o0]  + bhu0);
            float u1 = sigmoid_fast(s[3] + gb[513 + o0]  + bhu1);
            float n0 = tanh_fast(s[4] + gb[1024 + o0] + r0 * bhn0);
            float n1 = tanh_fast(s[5] + gb[1025 + o0] + r1 * bhn1);
            float hv0 = (1.f - u0) * n0;
            float hv1 = (1.f - u1) * n1;
            h[b * 512 + o0]      = hv0;
            h[b * 512 + o0 + 1]  = hv1;
            ha[b * 512 + o0]     = hv0 + action[b * 512 + o0];
            ha[b * 512 + o0 + 1] = hv1 + action[b * 512 + o0 + 1];
        }
    }
}

// K4: dec (384 w) + rs1 (256) + Cc (512) = 1152 waves = 288 blocks
__global__ void __launch_bounds__(256) mid_kernel(
    const float* __restrict__ h, const float* __restrict__ ha,
    const float* __restrict__ dec_w, const float* __restrict__ dec_b, float* __restrict__ pred,
    const float* __restrict__ rs_w1, const float* __restrict__ rs_b1, float* __restrict__ r1,
    const float* __restrict__ sc_w1, float* __restrict__ Cc) {
    int wid = blockIdx.x * 4 + (threadIdx.x >> 6);
    if (wid < 384) {
        wgemm<2, 0>(wid, h, 512, dec_w, 512, dec_b, pred, 768, 96);
    } else if (wid < 640) {
        wgemm<2, 1>(wid - 384, h, 512, rs_w1, 512, rs_b1, r1, 512, 64);
    } else {
        wgemm<2, 0>(wid - 640, ha, 512, sc_w1 + 1024, 1536, nullptr, Cc, 1024, 128);
    }
}

// K5: exactly 2048 blocks (one residency round). Blocks 0..63 also run rs2 first.
// Score: block=(i, j0..j0+1); wave w -> b in [8w,8w+8); lane -> d [16*lane,+16).
// gelu(x) ~= x/(1+2^(NK*x)), paired rcp; f32x2 ops to coax v_pk_* packing.
__global__ void __launch_bounds__(256) score_rs2_kernel(
    const float* __restrict__ Ea, const float* __restrict__ Eb,
    const float* __restrict__ Cc, const float* __restrict__ w2,
    const float* __restrict__ b2, float* __restrict__ graph,
    const float* __restrict__ r1, const float* __restrict__ rs_w2,
    const float* __restrict__ rs_b2, float* __restrict__ reasoning) {
    int blk = blockIdx.x;
    if (blk < 64) {
        int wid = blk * 4 + (threadIdx.x >> 6);
        wgemm<2, 0>(wid, r1, 512, rs_w2, 512, rs_b2, reasoning, 512, 64);
    }
    int i = blk >> 5;
    int j0 = (blk & 31) << 1;
    int lane = threadIdx.x & 63;
    int wave = threadIdx.x >> 6;
    int d0 = lane << 4;

    const float4* Ea4  = reinterpret_cast<const float4*>(Ea + i * 1024 + d0);
    const float4* Eb04 = reinterpret_cast<const float4*>(Eb + j0 * 1024 + d0);
    const float4* Eb14 = reinterpret_cast<const float4*>(Eb + (j0 + 1) * 1024 + d0);
    const float4* W4   = reinterpret_cast<const float4*>(w2 + d0);

    f32x2 basea[8], baseb[8], wv[8];
#pragma unroll
    for (int c = 0; c < 4; ++c) {
        float4 e  = Ea4[c];
        float4 f0 = Eb04[c];
        float4 f1 = Eb14[c];
        float4 w  = W4[c];
        basea[2 * c]     = f32x2{e.x + f0.x, e.y + f0.y};
        basea[2 * c + 1] = f32x2{e.z + f0.z, e.w + f0.w};
        baseb[2 * c]     = f32x2{e.x + f1.x, e.y + f1.y};
        baseb[2 * c + 1] = f32x2{e.z + f1.z, e.w + f1.w};
        wv[2 * c]        = f32x2{w.x, w.y};
        wv[2 * c + 1]    = f32x2{w.z, w.w};
    }

    const f32x2 nk2  = f32x2{-2.4554274f, -2.4554274f};  // -1.702*log2(e)
    const f32x2 one2 = f32x2{1.f, 1.f};
    float bsc = b2[0];
    float gsum0 = 0.f, gsum1 = 0.f;
    const float4* p = reinterpret_cast<const float4*>(Cc + d0 + (wave * 8) * 1024);
    float4 m0 = p[0], m1 = p[1], m2 = p[2], m3 = p[3];

    for (int r = 0; r < 8; ++r) {
        f32x2 cc[8];
        cc[0] = f32x2{m0.x, m0.y}; cc[1] = f32x2{m0.z, m0.w};
        cc[2] = f32x2{m1.x, m1.y}; cc[3] = f32x2{m1.z, m1.w};
        cc[4] = f32x2{m2.x, m2.y}; cc[5] = f32x2{m2.z, m2.w};
        cc[6] = f32x2{m3.x, m3.y}; cc[7] = f32x2{m3.z, m3.w};
        if (r < 7) {
            const float4* q = reinterpret_cast<const float4*>(Cc + (wave * 8 + r + 1) * 1024 + d0);
            m0 = q[0]; m1 = q[1]; m2 = q[2]; m3 = q[3];
        }
        float s0 = 0.f, s1 = 0.f;
#pragma unroll
        for (int e = 0; e < 8; ++e) {
            f32x2 xA = cc[e] + basea[e];
            f32x2 xB = cc[e] + baseb[e];
            f32x2 aA = xA * nk2;
            f32x2 aB = xB * nk2;
            f32x2 tA, tB;
            tA.x = EXP2F(aA.x); tA.y = EXP2F(aA.y);
            tB.x = EXP2F(aB.x); tB.y = EXP2F(aB.y);
            f32x2 dA = tA + one2;
            f32x2 dB = tB + one2;
            f32x2 pA = xA * wv[e];
            f32x2 pB = xB * wv[e];
            float numA = fmaf(pA.x, dA.y, pA.y * dA.x);
            float numB = fmaf(pB.x, dB.y, pB.y * dB.x);
            float rrA = __builtin_amdgcn_rcpf(dA.x * dA.y);
            float rrB = __builtin_amdgcn_rcpf(dB.x * dB.y);
            s0 = fmaf(numA, rrA, s0);
            s1 = fmaf(numB, rrB, s1);
        }
#pragma unroll
        for (int m = 32; m >= 1; m >>= 1) {
            s0 += __shfl_xor(s0, m, 64);
            s1 += __shfl_xor(s1, m, 64);
        }
        if (lane == 0) {
            gsum0 += sigmoid_fast(s0 + bsc);
            gsum1 += sigmoid_fast(s1 + bsc);
        }
    }

    __shared__ float red[4][2];
    if (lane == 0) { red[wave][0] = gsum0; red[wave][1] = gsum1; }
    __syncthreads();
    if (threadIdx.x == 0) {
        graph[i * 64 + j0]     = (red[0][0] + red[1][0] + red[2][0] + red[3][0]) * 0.03125f;
        graph[i * 64 + j0 + 1] = (red[0][1] + red[1][1] + red[2][1] + red[3][1]) * 0.03125f;
    }
}

extern "C" void kernel_launch(void* const* d_in, const int* in_sizes, int n_in,
                              void* d_out, int out_size, void* d_ws, size_t ws_size,
                              hipStream_t stream) {
    const float* obs     = (const float*)d_in[0];
    const float* action  = (const float*)d_in[1];
    const float* embed   = (const float*)d_in[2];
    const float* sc_w1   = (const float*)d_in[3];
    const float* sc_b1   = (const float*)d_in[4];
    const float* sc_w2   = (const float*)d_in[5];
    const float* sc_b2   = (const float*)d_in[6];
    const float* enc_w1  = (const float*)d_in[7];
    const float* enc_b1  = (const float*)d_in[8];
    const float* enc_w2  = (const float*)d_in[9];
    const float* enc_b2  = (const float*)d_in[10];
    const float* gru_wih = (const float*)d_in[11];
    const float* gru_bih = (const float*)d_in[13];
    const float* gru_bhh = (const float*)d_in[14];
    const float* dec_w   = (const float*)d_in[15];
    const float* dec_b   = (const float*)d_in[16];
    const float* rs_w1   = (const float*)d_in[17];
    const float* rs_b1   = (const float*)d_in[18];
    const float* rs_w2   = (const float*)d_in[19];
    const float* rs_b2   = (const float*)d_in[20];

    float* ws = (float*)d_ws;
    float* h1  = ws + 0;        // 32x1024
    float* z   = ws + 32768;    // 32x512
    float* gia = ws + 49152;    // 32x1536
    float* ha  = ws + 98304;    // 32x512
    float* r1  = ws + 114688;   // 32x512
    float* Cc  = ws + 131072;   // 32x1024
    float* Ea  = ws + 163840;   // 64x1024
    float* Eb  = ws + 229376;   // 64x1024

    float* h_out     = (float*)d_out;
    float* pred      = h_out + 16384;
    float* graph     = h_out + 40960;
    float* reasoning = h_out + 45056;

    front_kernel<<<832, 256, 0, stream>>>(obs, enc_w1, enc_b1, h1,
                                          embed, sc_w1, sc_b1, Ea, Eb,
                                          action, gru_wih, gru_bih, gia);
    enc2_kernel<<<64, 256, 0, stream>>>(h1, enc_w2, enc_b2, z);
    gigru_kernel<<<256, 256, 0, stream>>>(z, gru_wih, gia, gru_bhh, action, h_out, ha);
    mid_kernel<<<288, 256, 0, stream>>>(h_out, ha, dec_w, dec_b, pred,
                                        rs_w1, rs_b1, r1, sc_w1, Cc);
    score_rs2_kernel<<<2048, 256, 0, stream>>>(Ea, Eb, Cc, sc_w2, sc_b2, graph,
                                               r1, rs_w2, rs_b2, reasoning);
}